// Round 4
// baseline (159.463 us; speedup 1.0000x reference)
//
#include <hip/hip_runtime.h>
#include <stdint.h>

// ContrastiveLoss (SimCLR NT-Xent), B=4096, D=128, T=0.5
// loss = (1/2B) * sum_k log(denom_k)  -  (1/(B*T)) * sum_i dot(z_i, z_j_i)

#define TEMP 0.5f
// exp(x/T) = exp2(x * log2(e)/T); T=0.5 -> scale = 2*log2(e)
#define EXP2_SCALE 2.885390081777927f
// sqrt(EXP2_SCALE), folded into the stored bf16 reps on BOTH sides so the
// MFMA result is already sim*EXP2_SCALE (saves one v_mul per sim element).
#define SCALE_HALF 1.6986435961843206f

typedef __bf16 bf16_t;
typedef bf16_t bf16x8 __attribute__((ext_vector_type(8)));
typedef float floatx4 __attribute__((ext_vector_type(4)));

__device__ __forceinline__ unsigned short f32_to_bf16(float f) {
    union { float f; uint32_t u; } v; v.f = f;
    uint32_t u = v.u;
    uint32_t r = (u + 0x7FFFu + ((u >> 16) & 1u)) >> 16;  // RNE
    return (unsigned short)r;
}

__device__ __forceinline__ bf16x8 as_bf16x8(uint4 v) {
    union { uint4 u; bf16x8 b; } c; c.u = v; return c.b;
}

// ---------------------------------------------------------------------------
// reps is stored in MFMA-FRAGMENT layout, not row-major:
//   16-row tile t, k-step ks (k = ks*32..+31), lane = quad*16+l16 holds 16 B
//   at byte address  t*4096 + ks*1024 + lane*16.
// A wave loading fragment (t, ks) reads one fully-contiguous 1 KB block
// (R2's row-major gathers touched 16 disjoint 64 B segments per instr).
// ---------------------------------------------------------------------------

// Kernel 1: per-row L2 normalize -> bf16 reps (frag layout, pre-scaled by
// SCALE_HALF); pos[i] = dot(z_i,z_j) exact fp32. Also zeroes rowsum + ticket.
__global__ __launch_bounds__(256) void norm_pos_kernel(
        const float* __restrict__ p1, const float* __restrict__ p2,
        unsigned short* __restrict__ reps, float* __restrict__ pos,
        float* __restrict__ rowsum, unsigned int* __restrict__ ticket, int B) {
    if (threadIdx.x < 8) rowsum[blockIdx.x * 8 + threadIdx.x] = 0.f;
    if (blockIdx.x == 0 && threadIdx.x == 8) *ticket = 0u;

    int wave = threadIdx.x >> 6;
    int lane = threadIdx.x & 63;
    int i = blockIdx.x * 4 + wave;
    if (i >= B) return;

    const float2* r1 = (const float2*)(p1 + (size_t)i * 128);
    const float2* r2 = (const float2*)(p2 + (size_t)i * 128);
    float2 a = r1[lane];
    float2 b = r2[lane];
    float ss1 = a.x * a.x + a.y * a.y;
    float ss2 = b.x * b.x + b.y * b.y;
    float d   = a.x * b.x + a.y * b.y;
    #pragma unroll
    for (int off = 32; off > 0; off >>= 1) {
        ss1 += __shfl_xor(ss1, off);
        ss2 += __shfl_xor(ss2, off);
        d   += __shfl_xor(d,   off);
    }
    float rn1 = rsqrtf(fmaxf(ss1, 1e-24f));
    float rn2 = rsqrtf(fmaxf(ss2, 1e-24f));
    float s1 = rn1 * SCALE_HALF;
    float s2 = rn2 * SCALE_HALF;

    // lane holds elements 2l,2l+1 of row i -> chunk j=l>>2, slot l&3.
    // frag addr in ushort2 (4 B) units: tile*1024 + ks*256 + quad*64 + l16*4 + slot
    int j = lane >> 2;
    size_t chunkOff = (size_t)(j >> 2) * 256 + (size_t)(j & 3) * 64 + (size_t)(i & 15) * 4 + (lane & 3);
    ushort2* rp = (ushort2*)reps;
    rp[(size_t)(i >> 4) * 1024 + chunkOff] =
        make_ushort2(f32_to_bf16(a.x * s1), f32_to_bf16(a.y * s1));
    rp[(size_t)((B + i) >> 4) * 1024 + chunkOff] =
        make_ushort2(f32_to_bf16(b.x * s2), f32_to_bf16(b.y * s2));

    if (lane == 0) pos[i] = d * rn1 * rn2;
}

// ---------------------------------------------------------------------------
// Kernel 2: sim+exp+rowsum, LDS-free, frag-layout coalesced loads. R2 geometry
// (best so far): wave = 4 row-tiles (64 rows, A in 64 VGPRs), block = 4 waves
// = 256-row panel x 256-col strip, grid 32x32. Finalize fused via ticket:
// the last block to finish computes the loss (saves a dispatch + gap).
// ---------------------------------------------------------------------------
__global__ __launch_bounds__(256) void simexp_kernel(
        const unsigned short* __restrict__ reps, float* __restrict__ rowsum,
        const float* __restrict__ pos, unsigned int* __restrict__ ticket,
        float* __restrict__ out, int nblocks, int B) {
    const int tid  = threadIdx.x;
    const int wave = tid >> 6;
    const int lane = tid & 63;
    const int quad = lane >> 4;
    const int l16  = lane & 15;

    const int rowTB = blockIdx.y * 16 + wave * 4;  // this wave's first row-tile
    const int colTB = blockIdx.x * 16;             // block's first col-tile
    const uint4* g = (const uint4*)reps;           // 16 B units

    // A-fragments: 4 row-tiles x 4 k-steps, each a contiguous 1 KB wave-load
    bf16x8 a[4][4];
    #pragma unroll
    for (int t = 0; t < 4; ++t)
        #pragma unroll
        for (int ks = 0; ks < 4; ++ks)
            a[t][ks] = as_bf16x8(g[(size_t)(rowTB + t) * 256 + ks * 64 + lane]);

    float rs[4][4];
    #pragma unroll
    for (int t = 0; t < 4; ++t)
        #pragma unroll
        for (int r = 0; r < 4; ++r) rs[t][r] = 0.f;

    const bool diagBlock = (blockIdx.x == blockIdx.y);  // panels are 256-aligned

    #pragma unroll 2
    for (int ct = 0; ct < 16; ++ct) {
        bf16x8 b[4];
        #pragma unroll
        for (int ks = 0; ks < 4; ++ks)
            b[ks] = as_bf16x8(g[(size_t)(colTB + ct) * 256 + ks * 64 + lane]);

        floatx4 acc[4];
        #pragma unroll
        for (int t = 0; t < 4; ++t) acc[t] = (floatx4){0.f, 0.f, 0.f, 0.f};

        #pragma unroll
        for (int ks = 0; ks < 4; ++ks)
            #pragma unroll
            for (int t = 0; t < 4; ++t)
                acc[t] = __builtin_amdgcn_mfma_f32_16x16x32_bf16(a[t][ks], b[ks], acc[t], 0, 0, 0);

        if (diagBlock) {
            const int c = blockIdx.x * 256 + ct * 16 + l16;
            #pragma unroll
            for (int t = 0; t < 4; ++t)
                #pragma unroll
                for (int reg = 0; reg < 4; ++reg) {
                    int r = blockIdx.y * 256 + wave * 64 + t * 16 + quad * 4 + reg;
                    rs[t][reg] += (r == c) ? 0.f : exp2f(acc[t][reg]);
                }
        } else {
            #pragma unroll
            for (int t = 0; t < 4; ++t)
                #pragma unroll
                for (int reg = 0; reg < 4; ++reg)
                    rs[t][reg] += exp2f(acc[t][reg]);
        }
    }

    // reduce across the 16 columns (l16) of each quad
    #pragma unroll
    for (int off = 1; off < 16; off <<= 1)
        #pragma unroll
        for (int t = 0; t < 4; ++t)
            #pragma unroll
            for (int reg = 0; reg < 4; ++reg)
                rs[t][reg] += __shfl_xor(rs[t][reg], off);

    if (l16 == 0) {
        #pragma unroll
        for (int t = 0; t < 4; ++t)
            #pragma unroll
            for (int reg = 0; reg < 4; ++reg)
                atomicAdd(&rowsum[blockIdx.y * 256 + wave * 64 + t * 16 + quad * 4 + reg],
                          rs[t][reg]);
    }

    // --- fused finalize: last block computes the loss ---
    __shared__ int lastFlag;
    __shared__ float wsum[4];
    __threadfence();          // release this block's rowsum atomics
    __syncthreads();          // all 4 waves' fences done before the ticket
    if (tid == 0) {
        unsigned int t = atomicAdd(ticket, 1u);
        lastFlag = (t == (unsigned int)(nblocks - 1)) ? 1 : 0;
    }
    __syncthreads();
    if (lastFlag) {
        __threadfence();      // acquire
        const int N2 = 2 * B;
        float v = 0.f;
        for (int k = tid; k < N2; k += 256) {
            float r = __hip_atomic_load(&rowsum[k], __ATOMIC_RELAXED,
                                        __HIP_MEMORY_SCOPE_AGENT);
            v += logf(r);
        }
        float p = 0.f;
        for (int i2 = tid; i2 < B; i2 += 256) p += pos[i2];
        float local = v * (1.0f / (float)N2) - p * (1.0f / ((float)B * TEMP));
        #pragma unroll
        for (int off = 32; off > 0; off >>= 1) local += __shfl_xor(local, off);
        if (lane == 0) wsum[wave] = local;
        __syncthreads();
        if (tid == 0) out[0] = wsum[0] + wsum[1] + wsum[2] + wsum[3];
    }
}

extern "C" void kernel_launch(void* const* d_in, const int* in_sizes, int n_in,
                              void* d_out, int out_size, void* d_ws, size_t ws_size,
                              hipStream_t stream) {
    const float* p1 = (const float*)d_in[0];
    const float* p2 = (const float*)d_in[1];
    float* out = (float*)d_out;

    const int B  = in_sizes[0] / 128;   // 4096
    const int N2 = 2 * B;               // 8192

    // ws: [reps bf16 frag: N2*256 B][rowsum: N2*4 B][pos: B*4 B][ticket: 4 B]
    unsigned short* reps = (unsigned short*)d_ws;
    float* rowsum = (float*)((char*)d_ws + (size_t)N2 * 256);
    float* pos    = rowsum + N2;
    unsigned int* ticket = (unsigned int*)(pos + B);

    norm_pos_kernel<<<dim3((B + 3) / 4), dim3(256), 0, stream>>>(
        p1, p2, reps, pos, rowsum, ticket, B);

    dim3 grid(N2 / 256, N2 / 256);  // 32 x 32 = 1024 blocks
    simexp_kernel<<<grid, dim3(256), 0, stream>>>(
        reps, rowsum, pos, ticket, out, grid.x * grid.y, B);
}

// Round 5
// 132.647 us; speedup vs baseline: 1.2022x; 1.2022x over previous
//
#include <hip/hip_runtime.h>
#include <stdint.h>

// ContrastiveLoss (SimCLR NT-Xent), B=4096, D=128, T=0.5
// loss = (1/2B) * sum_k log(denom_k)  -  (1/(B*T)) * sum_i dot(z_i, z_j_i)

#define TEMP 0.5f
// exp(x/T) = exp2(x * log2(e)/T); T=0.5 -> scale = 2*log2(e)
#define EXP2_SCALE 2.885390081777927f

typedef __bf16 bf16_t;
typedef bf16_t bf16x8 __attribute__((ext_vector_type(8)));
typedef float floatx4 __attribute__((ext_vector_type(4)));

__device__ __forceinline__ unsigned short f32_to_bf16(float f) {
    union { float f; uint32_t u; } v; v.f = f;
    uint32_t u = v.u;
    uint32_t r = (u + 0x7FFFu + ((u >> 16) & 1u)) >> 16;  // RNE
    return (unsigned short)r;
}

__device__ __forceinline__ bf16x8 as_bf16x8(uint4 v) {
    union { uint4 u; bf16x8 b; } c; c.u = v; return c.b;
}

// ---------------------------------------------------------------------------
// Kernel 1: per-row L2 normalize -> bf16 reps[2B][128] ROW-MAJOR (R4's
// fragment layout regressed 2x: 4KB-aligned tile phases hotspot L2 channels;
// row-major 256B-stride gathers spread across all channels). pos[i] =
// dot(z_i,z_j) exact fp32, plain store. Also zeroes rowsum[].
// ---------------------------------------------------------------------------
__global__ __launch_bounds__(256) void norm_pos_kernel(
        const float* __restrict__ p1, const float* __restrict__ p2,
        unsigned short* __restrict__ reps, float* __restrict__ pos,
        float* __restrict__ rowsum, int B) {
    if (threadIdx.x < 8) rowsum[blockIdx.x * 8 + threadIdx.x] = 0.f;

    int wave = threadIdx.x >> 6;
    int lane = threadIdx.x & 63;
    int i = blockIdx.x * 4 + wave;
    if (i >= B) return;

    const float2* r1 = (const float2*)(p1 + (size_t)i * 128);
    const float2* r2 = (const float2*)(p2 + (size_t)i * 128);
    float2 a = r1[lane];
    float2 b = r2[lane];
    float ss1 = a.x * a.x + a.y * a.y;
    float ss2 = b.x * b.x + b.y * b.y;
    float d   = a.x * b.x + a.y * b.y;
    #pragma unroll
    for (int off = 32; off > 0; off >>= 1) {
        ss1 += __shfl_xor(ss1, off);
        ss2 += __shfl_xor(ss2, off);
        d   += __shfl_xor(d,   off);
    }
    float rn1 = rsqrtf(fmaxf(ss1, 1e-24f));
    float rn2 = rsqrtf(fmaxf(ss2, 1e-24f));

    ushort2* z1 = (ushort2*)reps + (size_t)i * 64;
    ushort2* z2 = (ushort2*)reps + (size_t)(B + i) * 64;
    z1[lane] = make_ushort2(f32_to_bf16(a.x * rn1), f32_to_bf16(a.y * rn1));
    z2[lane] = make_ushort2(f32_to_bf16(b.x * rn2), f32_to_bf16(b.y * rn2));

    if (lane == 0) pos[i] = d * rn1 * rn2;
}

// ---------------------------------------------------------------------------
// Kernel 2: R2's exact structure (best measured: 57 us) with a NARROWER
// column strip: 128 cols instead of 256. Wave still owns 64 rows (4 A-tiles
// in 64 VGPRs, each B-frag feeds 4 MFMAs — R3 showed rows/wave must stay at
// 64 to keep VMEM-per-MFMA low), but total waves double: grid (64,32) =
// 2048 blocks x 4 waves = 8192 waves = 8/SIMD of work vs R2's 4 — attacks
// the latency-bound 20% occupancy without adding redundant B-loads per wave.
// ---------------------------------------------------------------------------
__global__ __launch_bounds__(256) void simexp_kernel(
        const unsigned short* __restrict__ reps,
        float* __restrict__ rowsum) {
    const int tid  = threadIdx.x;
    const int wave = tid >> 6;
    const int lane = tid & 63;
    const int quad = lane >> 4;
    const int l16  = lane & 15;

    const int rowWave = blockIdx.y * 256 + wave * 64;  // this wave's 64 rows
    const int colBase = blockIdx.x * 128;              // block's 128-col strip

    const uint4* g = (const uint4*)reps;  // 16 uint4 per 256-B row

    // A-fragments for 4 row-tiles x 4 k-steps (64 VGPRs), read once
    bf16x8 a[4][4];
    #pragma unroll
    for (int t = 0; t < 4; ++t)
        #pragma unroll
        for (int ks = 0; ks < 4; ++ks)
            a[t][ks] = as_bf16x8(g[(size_t)(rowWave + t * 16 + l16) * 16 + ks * 4 + quad]);

    float rs[4][4];
    #pragma unroll
    for (int t = 0; t < 4; ++t)
        #pragma unroll
        for (int r = 0; r < 4; ++r) rs[t][r] = 0.f;

    // does this block's 256-row panel contain the 128-col strip's diagonal?
    const bool diagBlock = ((int)(blockIdx.x >> 1) == (int)blockIdx.y);

    #pragma unroll 2
    for (int ctile = 0; ctile < 8; ++ctile) {
        const int colT = colBase + ctile * 16;
        bf16x8 b[4];
        #pragma unroll
        for (int ks = 0; ks < 4; ++ks)
            b[ks] = as_bf16x8(g[(size_t)(colT + l16) * 16 + ks * 4 + quad]);

        floatx4 acc[4];
        #pragma unroll
        for (int t = 0; t < 4; ++t) acc[t] = (floatx4){0.f, 0.f, 0.f, 0.f};

        #pragma unroll
        for (int ks = 0; ks < 4; ++ks)
            #pragma unroll
            for (int t = 0; t < 4; ++t)
                acc[t] = __builtin_amdgcn_mfma_f32_16x16x32_bf16(a[t][ks], b[ks], acc[t], 0, 0, 0);

        const int c = colT + l16;  // this lane's output column
        if (diagBlock) {
            #pragma unroll
            for (int t = 0; t < 4; ++t)
                #pragma unroll
                for (int reg = 0; reg < 4; ++reg) {
                    int r = rowWave + t * 16 + quad * 4 + reg;
                    float e = (r == c) ? 0.f : exp2f(acc[t][reg] * EXP2_SCALE);
                    rs[t][reg] += e;
                }
        } else {
            #pragma unroll
            for (int t = 0; t < 4; ++t)
                #pragma unroll
                for (int reg = 0; reg < 4; ++reg)
                    rs[t][reg] += exp2f(acc[t][reg] * EXP2_SCALE);
        }
    }

    // reduce across the 16 columns (l16 lanes) of each quad
    #pragma unroll
    for (int off = 1; off < 16; off <<= 1)
        #pragma unroll
        for (int t = 0; t < 4; ++t)
            #pragma unroll
            for (int reg = 0; reg < 4; ++reg)
                rs[t][reg] += __shfl_xor(rs[t][reg], off);

    if (l16 == 0) {
        #pragma unroll
        for (int t = 0; t < 4; ++t)
            #pragma unroll
            for (int reg = 0; reg < 4; ++reg)
                atomicAdd(&rowsum[rowWave + t * 16 + quad * 4 + reg], rs[t][reg]);
    }
}

// ---------------------------------------------------------------------------
// Kernel 3: single block; out[0] = mean(log(rowsum)) - sum(pos)/(B*T).
// ---------------------------------------------------------------------------
__global__ __launch_bounds__(1024) void finalize_kernel(
        const float* __restrict__ rowsum, const float* __restrict__ pos,
        float* __restrict__ out, int N2, int B) {
    float v = 0.f;
    for (int k = threadIdx.x; k < N2; k += 1024) v += logf(rowsum[k]);
    float p = 0.f;
    for (int i = threadIdx.x; i < B; i += 1024) p += pos[i];
    float local = v * (1.0f / (float)N2) - p * (1.0f / ((float)B * TEMP));

    #pragma unroll
    for (int off = 32; off > 0; off >>= 1) local += __shfl_xor(local, off);

    __shared__ float wsum[16];
    int wave = threadIdx.x >> 6, lane = threadIdx.x & 63;
    if (lane == 0) wsum[wave] = local;
    __syncthreads();
    if (threadIdx.x == 0) {
        float s = 0.f;
        for (int i = 0; i < 16; ++i) s += wsum[i];
        out[0] = s;
    }
}

extern "C" void kernel_launch(void* const* d_in, const int* in_sizes, int n_in,
                              void* d_out, int out_size, void* d_ws, size_t ws_size,
                              hipStream_t stream) {
    const float* p1 = (const float*)d_in[0];
    const float* p2 = (const float*)d_in[1];
    float* out = (float*)d_out;

    const int B  = in_sizes[0] / 128;   // 4096
    const int N2 = 2 * B;               // 8192

    // ws layout: [reps bf16: N2*256 B][rowsum fp32: N2*4 B][pos fp32: B*4 B]
    unsigned short* reps = (unsigned short*)d_ws;
    float* rowsum = (float*)((char*)d_ws + (size_t)N2 * 256);
    float* pos    = rowsum + N2;

    norm_pos_kernel<<<dim3((B + 3) / 4), dim3(256), 0, stream>>>(p1, p2, reps, pos, rowsum, B);

    dim3 grid(N2 / 128, N2 / 256);  // 64 x 32 = 2048 blocks, 8192 waves
    simexp_kernel<<<grid, dim3(256), 0, stream>>>(reps, rowsum);

    finalize_kernel<<<dim3(1), dim3(1024), 0, stream>>>(rowsum, pos, out, N2, B);
}